// Round 5
// baseline (288.271 us; speedup 1.0000x reference)
//
#include <hip/hip_runtime.h>

#define D_DIM 2048
#define E_DIM 64
#define BT 256                   // tokens per block
#define DSPLIT 4
#define DCH (D_DIM / DSPLIT)     // 512
#define DK 16                    // depth per LDS tile
#define NTILE (DCH / DK)         // 32
#define XB (BT * DK * 4)         // 16384 B
#define WB (E_DIM * DK * 4)      // 4096 B
#define BUFB (XB + WB)           // 20480 B
#define NBUF 4                   // 81920 B total LDS

typedef __attribute__((address_space(3))) char as3_char;
typedef __attribute__((address_space(1))) const char as1_char;

// Block (bx,by): tokens [bx*256, +256) x all 64 experts over D-chunk
// [by*512, +512). Partials land in d_out's 4 N*E regions (postprocess
// consumes them in place). 4-buffer ring, counted vmcnt (never 0 in the
// main loop) + RAW s_barrier — __syncthreads would emit an implicit
// vmcnt(0) drain and serialize the pipeline (the m97-structure stall).
__global__ __launch_bounds__(256, 1) void router_gemm(
    const float* __restrict__ x, const float* __restrict__ w,
    float* __restrict__ out, int N) {
  __shared__ __align__(16) char lds[NBUF][BUFB];
  const int tid = threadIdx.x;
  const int l = tid & 63;
  const int wv = tid >> 6;
  const int tbase = blockIdx.x * BT;
  const int dbase = blockIdx.y * DCH;

  // ---- staging: linear LDS dest; source pre-swizzled so stored chunk s of
  // row r holds global chunk s ^ ((r>>1)&3)  (rows are 64 B = 4 chunks).
  // Per 1024B instr: lane l -> row-in-group l>>2, stored chunk l&3;
  // ((row>>1)&3) folds to (l>>3)&3.
  const int scol = ((l & 3) ^ ((l >> 3) & 3)) * 4;  // floats
  const float* xsrc[4];
#pragma unroll
  for (int q = 0; q < 4; ++q) {
    int row = (wv * 4 + q) * 16 + (l >> 2);
    xsrc[q] = x + (size_t)(tbase + row) * D_DIM + dbase + scol;
  }
  const float* wsrc = w + (size_t)(wv * 16 + (l >> 2)) * D_DIM + dbase + scol;

  auto STAGE = [&](int b, int t) {
    const int d0 = t * DK;
#pragma unroll
    for (int q = 0; q < 4; ++q)
      __builtin_amdgcn_global_load_lds((as1_char*)(const char*)(xsrc[q] + d0),
                                       (as3_char*)&lds[b][(wv * 4 + q) * 1024],
                                       16, 0, 0);
    __builtin_amdgcn_global_load_lds((as1_char*)(const char*)(wsrc + d0),
                                     (as3_char*)&lds[b][XB + wv * 1024], 16, 0, 0);
  };

  // ---- compute mapping: thread (tg,eg) owns tokens {tg+32i} x experts
  // {eg*8+j}. Row base is 64B-aligned; swizzle lives in byte bits 4-5, so
  // read addr = base ^ (d4<<4) fetches global depth-chunk d4.
  const int tg = tid & 31;
  const int eg = tid >> 5;
  int xoff[8], woff[8];
#pragma unroll
  for (int i = 0; i < 8; ++i)
    xoff[i] = (tg + 32 * i) * 64 + (((tg >> 1) & 3) << 4);
#pragma unroll
  for (int j = 0; j < 8; ++j) {
    int e = eg * 8 + j;
    woff[j] = XB + e * 64 + (((e >> 1) & 3) << 4);
  }

  float acc[8][8];
#pragma unroll
  for (int i = 0; i < 8; ++i)
#pragma unroll
    for (int j = 0; j < 8; ++j) acc[i][j] = 0.f;

  // prologue: fill pipeline 3 deep (15 loads/wave outstanding)
  STAGE(0, 0);
  STAGE(1, 1);
  STAGE(2, 2);

  for (int t = 0; t < NTILE; ++t) {
    // counted wait: stage(t) complete, stages t+1..t+3 stay in flight
    if (t + 2 < NTILE) {
      asm volatile("s_waitcnt vmcnt(10)" ::: "memory");
    } else if (t + 2 == NTILE) {
      asm volatile("s_waitcnt vmcnt(5)" ::: "memory");
    } else {
      asm volatile("s_waitcnt vmcnt(0)" ::: "memory");
    }
    __builtin_amdgcn_s_barrier();           // raw barrier: no implicit drain
    __builtin_amdgcn_sched_barrier(0);      // keep STAGE below the barrier
    if (t + 3 < NTILE) STAGE((t + 3) & 3, t + 3);  // refill ring (issue-early)

    const char* buf = lds[t & 3];
#pragma unroll
    for (int d4 = 0; d4 < 4; ++d4) {
      const int dx = d4 << 4;
      float4 xv[8], wvv[8];
#pragma unroll
      for (int i = 0; i < 8; ++i)
        xv[i] = *(const float4*)(buf + (xoff[i] ^ dx));
#pragma unroll
      for (int j = 0; j < 8; ++j)
        wvv[j] = *(const float4*)(buf + (woff[j] ^ dx));
#pragma unroll
      for (int i = 0; i < 8; ++i)
#pragma unroll
        for (int j = 0; j < 8; ++j) {
          acc[i][j] = fmaf(xv[i].x, wvv[j].x, acc[i][j]);
          acc[i][j] = fmaf(xv[i].y, wvv[j].y, acc[i][j]);
          acc[i][j] = fmaf(xv[i].z, wvv[j].z, acc[i][j]);
          acc[i][j] = fmaf(xv[i].w, wvv[j].w, acc[i][j]);
        }
    }
    // no end-of-tile drain: next iteration's counted vmcnt + raw barrier
    // (plus FMA data-dependence on the ds_reads) provide the ordering.
  }

  // partial store: region = blockIdx.y, contiguous experts -> 2 float4/row
  float* part = out + (size_t)blockIdx.y * ((size_t)N * E_DIM);
#pragma unroll
  for (int i = 0; i < 8; ++i) {
    size_t o = (size_t)(tbase + tg + 32 * i) * E_DIM + eg * 8;
    *(float4*)(part + o) = make_float4(acc[i][0], acc[i][1], acc[i][2], acc[i][3]);
    *(float4*)(part + o + 4) = make_float4(acc[i][4], acc[i][5], acc[i][6], acc[i][7]);
  }
}

__global__ __launch_bounds__(256) void postprocess(float* out, float* ws, int N) {
  const int lane = threadIdx.x & 63;
  const int wv = threadIdx.x >> 6;
  const size_t NE = (size_t)N * E_DIM;
  float* disp = out;               // holds partial 0 on entry
  float* comb = out + NE;          // partial 1
  float* logits_o = out + 2 * NE;  // partial 2
  float* probs_o = out + 3 * NE;   // partial 3
  float* idx_o = out + 4 * NE + 1;
  float* pn_o = out + 4 * NE + 1 + 2 * (size_t)N;

  float expsum = 0.f;  // per-lane (= per-expert) prob sum over this wave's tokens
  const int t0 = blockIdx.x * 64 + wv * 16;
  for (int k = 0; k < 16; ++k) {
    const size_t t = (size_t)(t0 + k);
    const size_t o = t * E_DIM + lane;
    float lv = (disp[o] + comb[o]) + (logits_o[o] + probs_o[o]);
    logits_o[o] = lv;  // all 4 partials for this token already read
    float m = lv;
#pragma unroll
    for (int off = 32; off; off >>= 1) m = fmaxf(m, __shfl_xor(m, off));
    float p = __expf(lv - m);
    float s = p;
#pragma unroll
    for (int off = 32; off; off >>= 1) s += __shfl_xor(s, off);
    float prob = p / s;
    probs_o[o] = prob;
    expsum += prob;

    // packed key: prob bits | (63-lane) -> lowest index wins ties (jax top_k)
    unsigned long long key =
        ((unsigned long long)__float_as_uint(prob) << 32) | (unsigned)(63 - lane);
    unsigned long long k1 = key;
#pragma unroll
    for (int off = 32; off; off >>= 1) {
      unsigned long long v = __shfl_xor(k1, off);
      if (v > k1) k1 = v;
    }
    int i1 = 63 - (int)(k1 & 63);
    unsigned long long k2 = (lane == i1) ? 0ull : key;
#pragma unroll
    for (int off = 32; off; off >>= 1) {
      unsigned long long v = __shfl_xor(k2, off);
      if (v > k2) k2 = v;
    }
    int i2 = 63 - (int)(k2 & 63);
    float p1 = __uint_as_float((unsigned)(k1 >> 32));
    float p2 = __uint_as_float((unsigned)(k2 >> 32));
    float inv = 1.0f / (p1 + p2);
    float pn1 = p1 * inv, pn2 = p2 * inv;
    float dval = (lane == i1) ? pn1 : ((lane == i2) ? pn2 : 0.f);
    disp[o] = dval;
    comb[o] = dval;
    if (lane == 0) {
      idx_o[2 * t] = (float)i1;
      idx_o[2 * t + 1] = (float)i2;
      pn_o[2 * t] = pn1;
      pn_o[2 * t + 1] = pn2;
    }
  }

  __shared__ float aux_s[4][64];
  aux_s[wv][lane] = expsum;
  __syncthreads();
  if (threadIdx.x < 64) {
    float s = aux_s[0][threadIdx.x] + aux_s[1][threadIdx.x] +
              aux_s[2][threadIdx.x] + aux_s[3][threadIdx.x];
    ws[(size_t)blockIdx.x * 64 + threadIdx.x] = s;  // per-block expert partials
  }
}

__global__ __launch_bounds__(256) void finalize_aux(const float* __restrict__ ws,
                                                    float* __restrict__ auxp,
                                                    int nblocks, int N) {
  __shared__ float red[256];
  const int e = threadIdx.x & 63;
  const int part = threadIdx.x >> 6;
  float s = 0.f;
  for (int b = part; b < nblocks; b += 4) s += ws[(size_t)b * 64 + e];
  red[threadIdx.x] = s;
  __syncthreads();
  if (threadIdx.x < 64) {
    float tot = red[e] + red[64 + e] + red[128 + e] + red[192 + e];
    float pb = tot / (float)N;
    float v = pb * pb;  // aux = mean_e(E*pb^2) = sum_e pb^2
#pragma unroll
    for (int off = 32; off; off >>= 1) v += __shfl_xor(v, off);
    if (threadIdx.x == 0) *auxp = v;
  }
}

extern "C" void kernel_launch(void* const* d_in, const int* in_sizes, int n_in,
                              void* d_out, int out_size, void* d_ws, size_t ws_size,
                              hipStream_t stream) {
  (void)n_in; (void)out_size; (void)ws_size;
  const float* x = (const float*)d_in[0];
  const float* w = (const float*)d_in[1];
  float* out = (float*)d_out;
  const int N = in_sizes[0] / D_DIM;  // 16384
  const int npb = N / 64;             // postprocess blocks (256)

  dim3 gg(N / BT, DSPLIT);  // 64 x 4 = 256 blocks
  router_gemm<<<gg, dim3(256), 0, stream>>>(x, w, out, N);
  postprocess<<<dim3(npb), dim3(256), 0, stream>>>(out, (float*)d_ws, N);
  finalize_aux<<<dim3(1), dim3(256), 0, stream>>>((const float*)d_ws,
                                                  out + 4 * (size_t)N * E_DIM,
                                                  npb, N);
}

// Round 6
// 276.410 us; speedup vs baseline: 1.0429x; 1.0429x over previous
//
#include <hip/hip_runtime.h>

#define D_DIM 2048
#define E_DIM 64
#define BT 256                   // tokens per block
#define DSPLIT 4
#define DCH (D_DIM / DSPLIT)     // 512
#define DK 16                    // depth per LDS tile
#define NTILE (DCH / DK)         // 32
#define XB (BT * DK * 4)         // 16384 B
#define WB (E_DIM * DK * 4)      // 4096 B
#define BUFB (XB + WB)           // 20480 B
#define NBUF 4                   // 81920 B total LDS

typedef __attribute__((address_space(3))) char as3_char;
typedef __attribute__((address_space(1))) const char as1_char;

// Block (bx,by): tokens [bx*256,+256) x all 64 experts over D-chunk
// [by*512,+512). Partials land in d_out's 4 N*E regions. 4-buffer ring,
// counted vmcnt, raw s_barrier. 512 threads = 8 waves = 2 waves/SIMD:
// R3/R5 ran 1 wave/SIMD and were latency-bound (VALUBusy 32%) — TLP is
// the fix, not deeper pipelining.
__global__ __launch_bounds__(512, 1) void router_gemm(
    const float* __restrict__ x, const float* __restrict__ w,
    float* __restrict__ out, int N) {
  __shared__ __align__(16) char lds[NBUF][BUFB];
  const int tid = threadIdx.x;
  const int l = tid & 63;
  const int wv = tid >> 6;           // 0..7
  const int tbase = blockIdx.x * BT;
  const int dbase = blockIdx.y * DCH;

  // ---- staging: linear LDS dest; source pre-swizzled so stored chunk s of
  // row r holds global chunk s ^ ((r>>1)&3) (rows are 64 B = 4 chunks).
  // Per 1024 B instr: lane l -> row-in-group l>>2, stored chunk l&3.
  const int scol = ((l & 3) ^ ((l >> 3) & 3)) * 4;  // floats
  const float* xsrc[2];
#pragma unroll
  for (int q = 0; q < 2; ++q) {
    int row = (wv * 2 + q) * 16 + (l >> 2);         // 16 groups cover 256 rows
    xsrc[q] = x + (size_t)(tbase + row) * D_DIM + dbase + scol;
  }
  const float* wsrc = w + (size_t)(wv * 16 + (l >> 2)) * D_DIM + dbase + scol;

  auto STAGE = [&](int b, int t) {
    const int d0 = t * DK;
#pragma unroll
    for (int q = 0; q < 2; ++q)
      __builtin_amdgcn_global_load_lds(
          (as1_char*)(const char*)(xsrc[q] + d0),
          (as3_char*)&lds[b][(wv * 2 + q) * 1024], 16, 0, 0);
    if (wv < 4)  // 4 w-loads, waves 0-3 (wave-uniform branch)
      __builtin_amdgcn_global_load_lds((as1_char*)(const char*)(wsrc + d0),
                                       (as3_char*)&lds[b][XB + wv * 1024], 16,
                                       0, 0);
  };

  // ---- compute mapping: thread (tg,eg) owns tokens {tg+32i, i<8} x experts
  // {eg*4+j, j<4}. Row base 64B-aligned; swizzle in byte bits 4-5 -> read
  // addr = base ^ (d4<<4) fetches global depth-chunk d4.
  const int tg = tid & 31;
  const int eg = tid >> 5;  // 0..15
  int xoff[8], woff[4];
#pragma unroll
  for (int i = 0; i < 8; ++i)
    xoff[i] = (tg + 32 * i) * 64 + (((tg >> 1) & 3) << 4);
#pragma unroll
  for (int j = 0; j < 4; ++j) {
    int e = eg * 4 + j;
    woff[j] = XB + e * 64 + (((e >> 1) & 3) << 4);
  }

  float acc[8][4];
#pragma unroll
  for (int i = 0; i < 8; ++i)
#pragma unroll
    for (int j = 0; j < 4; ++j) acc[i][j] = 0.f;

  // prologue: fill pipeline 3 deep
  STAGE(0, 0);
  STAGE(1, 1);
  STAGE(2, 2);

  for (int t = 0; t < NTILE; ++t) {
    // counted wait: stage t complete, later stages stay in flight.
    // Waves 0-3 issue 3 loads/tile, waves 4-7 issue 2 (wave-uniform branch).
    if (t + 3 <= NTILE) {
      if (wv < 4) asm volatile("s_waitcnt vmcnt(6)" ::: "memory");
      else        asm volatile("s_waitcnt vmcnt(4)" ::: "memory");
    } else if (t == NTILE - 2) {
      if (wv < 4) asm volatile("s_waitcnt vmcnt(3)" ::: "memory");
      else        asm volatile("s_waitcnt vmcnt(2)" ::: "memory");
    } else {
      asm volatile("s_waitcnt vmcnt(0)" ::: "memory");
    }
    __builtin_amdgcn_s_barrier();       // raw barrier: no implicit drain
    __builtin_amdgcn_sched_barrier(0);  // pin STAGE/ds_reads below barrier
    if (t + 3 < NTILE) STAGE((t + 3) & 3, t + 3);  // refill ring

    const char* buf = lds[t & 3];
#pragma unroll
    for (int d4 = 0; d4 < 4; ++d4) {
      const int dx = d4 << 4;
      float4 xv[8], wvv[4];
#pragma unroll
      for (int i = 0; i < 8; ++i)
        xv[i] = *(const float4*)(buf + (xoff[i] ^ dx));
#pragma unroll
      for (int j = 0; j < 4; ++j)
        wvv[j] = *(const float4*)(buf + (woff[j] ^ dx));
#pragma unroll
      for (int i = 0; i < 8; ++i)
#pragma unroll
        for (int j = 0; j < 4; ++j) {
          acc[i][j] = fmaf(xv[i].x, wvv[j].x, acc[i][j]);
          acc[i][j] = fmaf(xv[i].y, wvv[j].y, acc[i][j]);
          acc[i][j] = fmaf(xv[i].z, wvv[j].z, acc[i][j]);
          acc[i][j] = fmaf(xv[i].w, wvv[j].w, acc[i][j]);
        }
    }
  }

  // partial store: region = blockIdx.y, one float4 per (thread, token-row)
  float* part = out + (size_t)blockIdx.y * ((size_t)N * E_DIM);
#pragma unroll
  for (int i = 0; i < 8; ++i) {
    size_t o = (size_t)(tbase + tg + 32 * i) * E_DIM + eg * 4;
    *(float4*)(part + o) = make_float4(acc[i][0], acc[i][1], acc[i][2], acc[i][3]);
  }
}

__global__ __launch_bounds__(256) void postprocess(float* out, float* ws, int N) {
  const int lane = threadIdx.x & 63;
  const int wv = threadIdx.x >> 6;
  const size_t NE = (size_t)N * E_DIM;
  float* disp = out;               // holds partial 0 on entry
  float* comb = out + NE;          // partial 1
  float* logits_o = out + 2 * NE;  // partial 2
  float* probs_o = out + 3 * NE;   // partial 3
  float* idx_o = out + 4 * NE + 1;
  float* pn_o = out + 4 * NE + 1 + 2 * (size_t)N;

  float expsum = 0.f;  // per-lane (= per-expert) prob sum over this wave's tokens
  const int t0 = blockIdx.x * 64 + wv * 16;
  for (int k = 0; k < 16; ++k) {
    const size_t t = (size_t)(t0 + k);
    const size_t o = t * E_DIM + lane;
    float lv = (disp[o] + comb[o]) + (logits_o[o] + probs_o[o]);
    logits_o[o] = lv;  // all 4 partials for this token already read
    float m = lv;
#pragma unroll
    for (int off = 32; off; off >>= 1) m = fmaxf(m, __shfl_xor(m, off));
    float p = __expf(lv - m);
    float s = p;
#pragma unroll
    for (int off = 32; off; off >>= 1) s += __shfl_xor(s, off);
    float prob = p / s;
    probs_o[o] = prob;
    expsum += prob;

    // packed key: prob bits | (63-lane) -> lowest index wins ties (jax top_k)
    unsigned long long key =
        ((unsigned long long)__float_as_uint(prob) << 32) | (unsigned)(63 - lane);
    unsigned long long k1 = key;
#pragma unroll
    for (int off = 32; off; off >>= 1) {
      unsigned long long v = __shfl_xor(k1, off);
      if (v > k1) k1 = v;
    }
    int i1 = 63 - (int)(k1 & 63);
    unsigned long long k2 = (lane == i1) ? 0ull : key;
#pragma unroll
    for (int off = 32; off; off >>= 1) {
      unsigned long long v = __shfl_xor(k2, off);
      if (v > k2) k2 = v;
    }
    int i2 = 63 - (int)(k2 & 63);
    float p1 = __uint_as_float((unsigned)(k1 >> 32));
    float p2 = __uint_as_float((unsigned)(k2 >> 32));
    float inv = 1.0f / (p1 + p2);
    float pn1 = p1 * inv, pn2 = p2 * inv;
    float dval = (lane == i1) ? pn1 : ((lane == i2) ? pn2 : 0.f);
    disp[o] = dval;
    comb[o] = dval;
    if (lane == 0) {
      idx_o[2 * t] = (float)i1;
      idx_o[2 * t + 1] = (float)i2;
      pn_o[2 * t] = pn1;
      pn_o[2 * t + 1] = pn2;
    }
  }

  __shared__ float aux_s[4][64];
  aux_s[wv][lane] = expsum;
  __syncthreads();
  if (threadIdx.x < 64) {
    float s = aux_s[0][threadIdx.x] + aux_s[1][threadIdx.x] +
              aux_s[2][threadIdx.x] + aux_s[3][threadIdx.x];
    ws[(size_t)blockIdx.x * 64 + threadIdx.x] = s;  // per-block expert partials
  }
}

__global__ __launch_bounds__(256) void finalize_aux(const float* __restrict__ ws,
                                                    float* __restrict__ auxp,
                                                    int nblocks, int N) {
  __shared__ float red[256];
  const int e = threadIdx.x & 63;
  const int part = threadIdx.x >> 6;
  float s = 0.f;
  for (int b = part; b < nblocks; b += 4) s += ws[(size_t)b * 64 + e];
  red[threadIdx.x] = s;
  __syncthreads();
  if (threadIdx.x < 64) {
    float tot = red[e] + red[64 + e] + red[128 + e] + red[192 + e];
    float pb = tot / (float)N;
    float v = pb * pb;  // aux = mean_e(E*pb^2) = sum_e pb^2
#pragma unroll
    for (int off = 32; off; off >>= 1) v += __shfl_xor(v, off);
    if (threadIdx.x == 0) *auxp = v;
  }
}

extern "C" void kernel_launch(void* const* d_in, const int* in_sizes, int n_in,
                              void* d_out, int out_size, void* d_ws, size_t ws_size,
                              hipStream_t stream) {
  (void)n_in; (void)out_size; (void)ws_size;
  const float* x = (const float*)d_in[0];
  const float* w = (const float*)d_in[1];
  float* out = (float*)d_out;
  const int N = in_sizes[0] / D_DIM;  // 16384
  const int npb = N / 64;             // postprocess blocks (256)

  dim3 gg(N / BT, DSPLIT);  // 64 x 4 = 256 blocks
  router_gemm<<<gg, dim3(512), 0, stream>>>(x, w, out, N);
  postprocess<<<dim3(npb), dim3(256), 0, stream>>>(out, (float*)d_ws, N);
  finalize_aux<<<dim3(1), dim3(256), 0, stream>>>((const float*)d_ws,
                                                  out + 4 * (size_t)N * E_DIM,
                                                  npb, N);
}